// Round 10
// baseline (254.484 us; speedup 1.0000x reference)
//
#include <hip/hip_runtime.h>

#define B 4
#define N 2048
#define MAXIT 11        // bodies it=0..10; launch it=11 is finalize-only
#define TOL 1e-4f
#define BT 512
#define NBLK 256
#define QPB 32         // queries per block
#define NSTR 64        // candidate stripes per block
#define CPS 32         // candidates per stripe
#define CPT 4          // candidates per thread (N/BT)

// ---------------- workspace layout (ping-pong partials: no memsets needed) ----
// [0,     12288) f32 GpA[64][4][12]   (G-partials: {sum m(3), sum m (x) p1(9)})
// [12288, 24576) f32 GpB[64][4][12]
// [24576, 25600) f32 errpA[256]       (per-block sum of sqrt(d2) over 32 queries)
// [25600, 26624) f32 errpB[256]
// [26624, 31232) f64 rc[B][12][12]    (cumulative R(9)+t(3) per batch per launch)
// [31232, 31280) f32 errs[12]
// [31280, 31284) int doneflag         (0 or finalize-launch-index+1)
// [31284, 31332) f32 p1s[B][3]        (sum of p1 per batch, written at it=0)

// ---------------- 3x3 helpers (double, thread-serial) ----------------
__device__ double det3(const double* M) {
    return M[0]*(M[4]*M[8]-M[5]*M[7])
         - M[1]*(M[3]*M[8]-M[5]*M[6])
         + M[2]*(M[3]*M[7]-M[4]*M[6]);
}

__device__ void svd3x3(const double* A, double* U, double* V, double* sig) {
    double S[9];
    for (int i = 0; i < 3; ++i)
        for (int j = 0; j < 3; ++j) {
            double s = 0.0;
            for (int k = 0; k < 3; ++k) s += A[k*3+i] * A[k*3+j];
            S[i*3+j] = s;
        }
    double Vm[9] = {1,0,0, 0,1,0, 0,0,1};
    for (int sweep = 0; sweep < 30; ++sweep) {
        double off = fabs(S[1]) + fabs(S[2]) + fabs(S[5]);
        double base = fabs(S[0]) + fabs(S[4]) + fabs(S[8]);
        if (off <= 1e-15 * base) break;
        for (int pi = 0; pi < 3; ++pi) {
            const int p = (pi == 2) ? 1 : 0;
            const int q = (pi == 0) ? 1 : 2;
            double apq = S[p*3+q];
            if (apq == 0.0) continue;
            double app = S[p*3+p], aqq = S[q*3+q];
            double tau = (aqq - app) / (2.0 * apq);
            double tt  = ((tau >= 0.0) ? 1.0 : -1.0) / (fabs(tau) + sqrt(1.0 + tau*tau));
            double c = 1.0 / sqrt(1.0 + tt*tt);
            double s = tt * c;
            for (int k = 0; k < 3; ++k) {
                double skp = S[k*3+p], skq = S[k*3+q];
                S[k*3+p] = c*skp - s*skq;
                S[k*3+q] = s*skp + c*skq;
            }
            for (int k = 0; k < 3; ++k) {
                double spk = S[p*3+k], sqk = S[q*3+k];
                S[p*3+k] = c*spk - s*sqk;
                S[q*3+k] = s*spk + c*sqk;
            }
            for (int k = 0; k < 3; ++k) {
                double vkp = Vm[k*3+p], vkq = Vm[k*3+q];
                Vm[k*3+p] = c*vkp - s*vkq;
                Vm[k*3+q] = s*vkp + c*vkq;
            }
        }
    }
    double lam[3] = {S[0], S[4], S[8]};
    int ord[3] = {0, 1, 2};
    for (int i = 0; i < 2; ++i)
        for (int j = i+1; j < 3; ++j)
            if (lam[ord[j]] > lam[ord[i]]) { int tmp = ord[i]; ord[i] = ord[j]; ord[j] = tmp; }
    for (int i = 0; i < 3; ++i) {
        int o = ord[i];
        double l = lam[o] > 0.0 ? lam[o] : 0.0;
        sig[i] = sqrt(l);
        for (int k = 0; k < 3; ++k) V[k*3+i] = Vm[k*3+o];
    }
    for (int i = 0; i < 3; ++i) {
        double u0 = 0, u1 = 0, u2 = 0;
        for (int k = 0; k < 3; ++k) {
            u0 += A[0*3+k] * V[k*3+i];
            u1 += A[1*3+k] * V[k*3+i];
            u2 += A[2*3+k] * V[k*3+i];
        }
        double nrm = sqrt(u0*u0 + u1*u1 + u2*u2);
        if (nrm > 1e-300) { u0 /= nrm; u1 /= nrm; u2 /= nrm; }
        else {
            double ax = U[0], ay = U[3], az = U[6];
            double bx = U[1], by = U[4], bz = U[7];
            u0 = ay*bz - az*by; u1 = az*bx - ax*bz; u2 = ax*by - ay*bx;
        }
        U[0*3+i] = u0; U[1*3+i] = u1; U[2*3+i] = u2;
    }
}

// R = V @ U^T (reference's R incl. the V[2][2]*=d quirk). Fast path det(H)>0:
// Newton polar iteration, fixed count (bit-identical across blocks).
__device__ void compute_R_f64(const double* H, double* R) {
    double nf = 0.0;
    for (int k = 0; k < 9; ++k) nf += H[k]*H[k];
    if (nf > 0.0) {
        const double sc = 1.0 / sqrt(nf * (1.0/3.0));
        double X[9];
        #pragma unroll
        for (int k = 0; k < 9; ++k) X[k] = H[k] * sc;
        const double d0 = det3(X);
        if (d0 > 1e-12) {
            for (int iter = 0; iter < 10; ++iter) {
                const double dt = det3(X);
                const double g = (iter < 4) ? cbrt(1.0 / dt) : 1.0;
                double Y[9];
                #pragma unroll
                for (int k = 0; k < 9; ++k) Y[k] = g * X[k];
                double C[9];
                C[0] = Y[4]*Y[8]-Y[5]*Y[7]; C[1] = Y[5]*Y[6]-Y[3]*Y[8]; C[2] = Y[3]*Y[7]-Y[4]*Y[6];
                C[3] = Y[2]*Y[7]-Y[1]*Y[8]; C[4] = Y[0]*Y[8]-Y[2]*Y[6]; C[5] = Y[1]*Y[6]-Y[0]*Y[7];
                C[6] = Y[1]*Y[5]-Y[2]*Y[4]; C[7] = Y[2]*Y[3]-Y[0]*Y[5]; C[8] = Y[0]*Y[4]-Y[1]*Y[3];
                const double inv = 1.0 / (dt * g * g * g);
                #pragma unroll
                for (int k = 0; k < 9; ++k) X[k] = 0.5 * (Y[k] + C[k] * inv);
            }
            R[0]=X[0]; R[1]=X[3]; R[2]=X[6];
            R[3]=X[1]; R[4]=X[4]; R[5]=X[7];
            R[6]=X[2]; R[7]=X[5]; R[8]=X[8];
            return;
        }
    }
    double U[9], V[9], sig[3];
    svd3x3(H, U, V, sig);
    double d = (det3(U) * det3(V) < 0.0) ? -1.0 : 1.0;
    V[2*3+2] *= d;
    for (int i = 0; i < 3; ++i)
        for (int j = 0; j < 3; ++j) {
            double s = 0.0;
            for (int k = 0; k < 3; ++k) s += V[i*3+k] * U[j*3+k];
            R[i*3+j] = s;
        }
}

__device__ inline float wred(float v) {
    v += __shfl_down(v, 32);
    v += __shfl_down(v, 16);
    v += __shfl_down(v, 8);
    v += __shfl_down(v, 4);
    v += __shfl_down(v, 2);
    v += __shfl_down(v, 1);
    return v;   // valid on lane 0 of each wave
}

__device__ __forceinline__ void tf3(const float* __restrict__ R, const float* __restrict__ T,
                                    float x, float y, float z,
                                    float& ox, float& oy, float& oz) {
    ox = x*R[0] + y*R[3] + z*R[6] + T[0];
    oy = x*R[1] + y*R[4] + z*R[7] + T[1];
    oz = x*R[2] + y*R[5] + z*R[8] + T[2];
}

// One launch per ICP iteration. 256 blocks x 512 threads: b = bid>>6, blk = bid&63.
// BT=512 widens the NN scan (64 stripes x 32 candidates: 128 evals/thread) and
// staging (4 loads/thread) at 8 waves/CU, while EVERY value-producing reduction
// (err tree, g12, p1s, finalize sums) stays gated to tid<256 with the identical
// lane mapping of the round-7/9 passing kernels -> bit-identical trajectory.
__global__ void __launch_bounds__(BT) k_iter(const float* __restrict__ p1,
                                             const float* __restrict__ p2,
                                             float* __restrict__ out,
                                             const float* __restrict__ rGp,
                                             float* __restrict__ wGp,
                                             const float* __restrict__ rerrp,
                                             float* __restrict__ werrp,
                                             double* __restrict__ rc,
                                             float* __restrict__ errs,
                                             int* __restrict__ doneflag,
                                             float* __restrict__ p1s,
                                             int it) {
    const int bid = blockIdx.x, tid = threadIdx.x;
    const int b = bid >> 6, blk = bid & 63;
    const int lane = tid & 63, wave = tid >> 6;

    __shared__ float4 sc4[N];              // 32 KB candidates, bank-rotated
    __shared__ float sScore[NSTR][QPB];    // 8 KB
    __shared__ int   sIdx[NSTR][QPB];      // 8 KB
    __shared__ float sPn[QPB], sD2[QPB];
    __shared__ int   sMi[QPB];
    __shared__ float sR[9], sT[3];
    __shared__ float lred[4][16];
    __shared__ int sFin;

    // ---------- T14 issue-early: R-independent register prefetch ----------
    float cvx[CPT], cvy[CPT], cvz[CPT];
    #pragma unroll
    for (int u = 0; u < CPT; ++u) {
        const float* cp = &p1[(b*N + tid + u*BT)*3];
        cvx[u] = cp[0]; cvy[u] = cp[1]; cvz[u] = cp[2];
    }
    const int qg = tid & 7, st = tid >> 3;   // 8 query-groups x 64 stripes
    float qx[4], qy[4], qz[4];
    #pragma unroll
    for (int k = 0; k < 4; ++k) {
        const float* pp = &p2[(b*N + blk*QPB + qg*4 + k)*3];
        qx[k] = pp[0]; qy[k] = pp[1]; qz[k] = pp[2];
    }

    if (it == 0) {
        if (tid == 0) {
            sR[0]=1.f; sR[1]=0.f; sR[2]=0.f;
            sR[3]=0.f; sR[4]=1.f; sR[5]=0.f;
            sR[6]=0.f; sR[7]=0.f; sR[8]=1.f;
            sT[0]=0.f; sT[1]=0.f; sT[2]=0.f;
            sFin = 0;
            if (bid == 0) {
                *doneflag = 0;
                for (int bb = 0; bb < B; ++bb) {
                    double* r0 = rc + (bb*12 + 0)*12;
                    r0[0]=1; r0[1]=0; r0[2]=0; r0[3]=0; r0[4]=1; r0[5]=0;
                    r0[6]=0; r0[7]=0; r0[8]=1; r0[9]=0; r0[10]=0; r0[11]=0;
                }
            }
        }
        __syncthreads();
    } else {
        // early exit only for launches strictly after the finalize launch
        { const int df = *doneflag; if (df != 0 && df <= it) return; }

        // ---------- phase 1: reduce partials, rebuild H, polar, compose ------
        // gated to tid<256: bit-identical reduction trees vs round-7/9 kernel
        if (tid < 256) {
            float g12[12];
            if (wave == 0) {
                const float* gp = rGp + (lane*4 + b)*12;    // Gp[blk=lane][b][12]
                const float4 a0 = *(const float4*)(gp);
                const float4 a1 = *(const float4*)(gp + 4);
                const float4 a2 = *(const float4*)(gp + 8);
                g12[0]=a0.x; g12[1]=a0.y; g12[2]=a0.z; g12[3]=a0.w;
                g12[4]=a1.x; g12[5]=a1.y; g12[6]=a1.z; g12[7]=a1.w;
                g12[8]=a2.x; g12[9]=a2.y; g12[10]=a2.z; g12[11]=a2.w;
                #pragma unroll
                for (int k = 0; k < 12; ++k) g12[k] = wred(g12[k]);
            }
            float er = rerrp[tid];
            er = wred(er);
            if (lane == 0) lred[wave][0] = er;
            __syncthreads();
            if (tid == 0) {
                const float ersum = lred[0][0]+lred[1][0]+lred[2][0]+lred[3][0];
                const float errcur = ersum / (float)(B*N);
                const float errprev = (it >= 2) ? errs[it-2] : 0.0f;
                const int done = (fabsf(errprev - errcur) < TOL) ? 1 : 0;
                errs[it-1] = errcur;

                const double* rp = rc + (b*12 + (it-1))*12;
                double RP[12];
                for (int k = 0; k < 12; ++k) RP[k] = rp[k];
                const double sm0 = g12[0], sm1 = g12[1], sm2 = g12[2];
                double G[9];
                for (int k = 0; k < 9; ++k) G[k] = (double)g12[3+k];
                const double p1b0 = (double)p1s[b*3+0]/N;
                const double p1b1 = (double)p1s[b*3+1]/N;
                const double p1b2 = (double)p1s[b*3+2]/N;
                const double c2d[3] = { sm0/N, sm1/N, sm2/N };
                const double smv[3] = { sm0, sm1, sm2 };
                double c1d[3], H[9];
                for (int k = 0; k < 3; ++k)
                    c1d[k] = p1b0*RP[0*3+k] + p1b1*RP[1*3+k] + p1b2*RP[2*3+k] + RP[9+k];
                for (int j = 0; j < 3; ++j)
                    for (int k = 0; k < 3; ++k) {
                        const double M = G[j*3+0]*RP[0*3+k] + G[j*3+1]*RP[1*3+k]
                                       + G[j*3+2]*RP[2*3+k] + smv[j]*RP[9+k];
                        H[j*3+k] = M - (double)N * c2d[j] * c1d[k];
                    }
                double Rinc[9], tinc[3];
                compute_R_f64(H, Rinc);
                for (int j = 0; j < 3; ++j)
                    tinc[j] = c2d[j] - (c1d[0]*Rinc[0*3+j] + c1d[1]*Rinc[1*3+j] + c1d[2]*Rinc[2*3+j]);
                double Rn[9], tn[3];
                for (int i = 0; i < 3; ++i)
                    for (int j = 0; j < 3; ++j)
                        Rn[i*3+j] = RP[i*3+0]*Rinc[0*3+j] + RP[i*3+1]*Rinc[1*3+j] + RP[i*3+2]*Rinc[2*3+j];
                for (int j = 0; j < 3; ++j)
                    tn[j] = RP[9+0]*Rinc[0*3+j] + RP[9+1]*Rinc[1*3+j] + RP[9+2]*Rinc[2*3+j] + tinc[j];
                double* rn = rc + (b*12 + it)*12;
                for (int k = 0; k < 9; ++k) { rn[k] = Rn[k]; sR[k] = (float)Rn[k]; }
                for (int k = 0; k < 3; ++k) { rn[9+k] = tn[k]; sT[k] = (float)tn[k]; }
                sFin = (done || it == MAXIT) ? 1 : 0;
            }
        } else {
            __syncthreads();   // matches the tid<256 __syncthreads above
        }
        __syncthreads();
    }

    if (it > 0 && sFin == 1) {
        // ---------- finalize: _get_transform(p1, temp_final) ----------
        if (blk != 0) return;
        float pv[16];
        #pragma unroll
        for (int k = 0; k < 16; ++k) pv[k] = 0.f;
        if (tid < 256) {
            for (int i = tid; i < N; i += 256) {
                const float* pp = &p1[(b*N + i)*3];
                const float px = pp[0], py = pp[1], pz = pp[2];
                float tx, ty, tz;
                tf3(sR, sT, px, py, pz, tx, ty, tz);        // temp_final
                pv[0] += tx; pv[1] += ty; pv[2] += tz;
                pv[3] += px; pv[4] += py; pv[5] += pz;
                pv[6] += tx*px;  pv[7]  += tx*py;  pv[8]  += tx*pz;
                pv[9] += ty*px;  pv[10] += ty*py;  pv[11] += ty*pz;
                pv[12]+= tz*px;  pv[13] += tz*py;  pv[14] += tz*pz;
            }
            #pragma unroll
            for (int k = 0; k < 15; ++k) pv[k] = wred(pv[k]);
            if (lane == 0) {
                #pragma unroll
                for (int k = 0; k < 15; ++k) lred[wave][k] = pv[k];
            }
        }
        __syncthreads();
        if (tid == 0) {
            float a[15];
            #pragma unroll
            for (int k = 0; k < 15; ++k)
                a[k] = lred[0][k] + lred[1][k] + lred[2][k] + lred[3][k];
            double c2d[3] = { (double)a[0]/N, (double)a[1]/N, (double)a[2]/N };
            double c1d[3] = { (double)a[3]/N, (double)a[4]/N, (double)a[5]/N };
            double H[9];
            for (int j = 0; j < 3; ++j)
                for (int k = 0; k < 3; ++k)
                    H[j*3+k] = (double)a[6 + j*3 + k] - (double)N * c2d[j] * c1d[k];
            double Rf[9];
            compute_R_f64(H, Rf);
            for (int i = 0; i < 3; ++i) {
                out[b*12 + i*4 + 0] = (float)Rf[i*3+0];
                out[b*12 + i*4 + 1] = (float)Rf[i*3+1];
                out[b*12 + i*4 + 2] = (float)Rf[i*3+2];
                const double tj = c2d[i] - (c1d[0]*Rf[0*3+i] + c1d[1]*Rf[1*3+i] + c1d[2]*Rf[2*3+i]);
                out[b*12 + i*4 + 3] = (float)tj;
            }
            *doneflag = it + 1;
        }
        return;
    }

    // ---------- phase 2: NN + fused partial reductions ----------
    // write-late: transform prefetched candidates with the just-computed R,t
    #pragma unroll
    for (int u = 0; u < CPT; ++u) {
        const int c = tid + u*BT;
        float cx, cy, cz;
        tf3(sR, sT, cvx[u], cvy[u], cvz[u], cx, cy, cz);
        const int s = c >> 6, jj = c & 63;
        sc4[s*64 + ((jj + s) & 63)] =
            make_float4(cx, cy, cz, 0.5f*(cx*cx + cy*cy + cz*cz));
    }
    __syncthreads();

    if (it == 0 && blk == 0 && tid < 256) {
        // p1 sums (identity at it=0 -> sc4 holds p1); stride 256: identical tree
        float sx = 0.f, sy = 0.f, sz = 0.f;
        for (int i = tid; i < N; i += 256) {
            const float4 v = sc4[i];
            sx += v.x; sy += v.y; sz += v.z;
        }
        sx = wred(sx); sy = wred(sy); sz = wred(sz);
        if (lane == 0) { lred[wave][0]=sx; lred[wave][1]=sy; lred[wave][2]=sz; }
    }

    if (st == 0) {
        #pragma unroll
        for (int k = 0; k < 4; ++k)
            sPn[qg*4 + k] = qx[k]*qx[k] + qy[k]*qy[k] + qz[k]*qz[k];
    }
    float bs[4]; int bj[4];
    #pragma unroll
    for (int k = 0; k < 4; ++k) { bs[k] = __uint_as_float(0x7f7fffffu); bj[k] = 0; }
    const int base = st * CPS;
    for (int j = 0; j < CPS; ++j) {
        const int cidx = base + j;                 // ascending candidate order
        const int g = cidx >> 6;
        const float4 cd = sc4[g*64 + (((cidx & 63) + g) & 63)];
        #pragma unroll
        for (int k = 0; k < 4; ++k) {
            float s = __builtin_fmaf(-qx[k], cd.x,
                      __builtin_fmaf(-qy[k], cd.y,
                      __builtin_fmaf(-qz[k], cd.z, cd.w)));
            if (s < bs[k]) { bs[k] = s; bj[k] = cidx; }
        }
    }
    #pragma unroll
    for (int k = 0; k < 4; ++k) {
        sScore[st][qg*4 + k] = bs[k];
        sIdx[st][qg*4 + k]   = bj[k];
    }
    __syncthreads();

    if (it == 0 && blk == 0 && tid == 0) {
        p1s[b*3+0] = lred[0][0]+lred[1][0]+lred[2][0]+lred[3][0];
        p1s[b*3+1] = lred[0][1]+lred[1][1]+lred[2][1]+lred[3][1];
        p1s[b*3+2] = lred[0][2]+lred[1][2]+lred[2][2]+lred[3][2];
    }

    if (tid < QPB) {
        // first-min across ascending stripes (= jnp.argmin first occurrence)
        float fb = sScore[0][tid]; int fj = sIdx[0][tid];
        #pragma unroll 8
        for (int s = 1; s < NSTR; ++s) {
            const float v = sScore[s][tid]; const int vi = sIdx[s][tid];
            if (v < fb || (v == fb && vi < fj)) { fb = v; fj = vi; }
        }
        const float d2 = fmaxf(__builtin_fmaf(2.0f, fb, sPn[tid]), 0.0f);
        sMi[tid] = fj;
        sD2[tid] = d2;
    }
    __syncthreads();

    // err partial: sum sqrt(d2) over this block's 32 queries (identical tree)
    if (tid < 64) {
        float e = (tid < QPB) ? sqrtf(sD2[tid]) : 0.f;
        e = wred(e);
        if (tid == 0) werrp[bid] = e;
    }

    // G partials: only batch-3 blocks (reference quirk: matched = p2[:, idx[-1]])
    if (b == 3 && tid < 128) {
        const int bb = tid >> 5, nl = tid & 31;
        const int mi = sMi[nl];
        const float* mp = &p2[(bb*N + mi)*3];
        const float mx = mp[0], my = mp[1], mz = mp[2];
        const float* pp = &p1[(bb*N + blk*QPB + nl)*3];
        const float qqx = pp[0], qqy = pp[1], qqz = pp[2];
        float g[12] = { mx, my, mz,
                        mx*qqx, mx*qqy, mx*qqz,
                        my*qqx, my*qqy, my*qqz,
                        mz*qqx, mz*qqy, mz*qqz };
        #pragma unroll
        for (int k = 0; k < 12; ++k) {
            #pragma unroll
            for (int o = 16; o; o >>= 1)
                g[k] += __shfl_xor(g[k], o, 32);
        }
        if (nl == 0) {
            float* gp = wGp + (blk*4 + bb)*12;
            #pragma unroll
            for (int k = 0; k < 12; ++k) gp[k] = g[k];
        }
    }
}

extern "C" void kernel_launch(void* const* d_in, const int* in_sizes, int n_in,
                              void* d_out, int out_size, void* d_ws, size_t ws_size,
                              hipStream_t stream) {
    const float* p1 = (const float*)d_in[0];
    const float* p2 = (const float*)d_in[1];
    float* out = (float*)d_out;
    float* GpA   = (float*)d_ws;
    float* GpB   = (float*)((char*)d_ws + 12288);
    float* errpA = (float*)((char*)d_ws + 24576);
    float* errpB = (float*)((char*)d_ws + 25600);
    double* rc   = (double*)((char*)d_ws + 26624);
    float* errs  = (float*)((char*)d_ws + 31232);
    int* doneflag = (int*)((char*)d_ws + 31280);
    float* p1s   = (float*)((char*)d_ws + 31284);

    for (int it = 0; it <= MAXIT; ++it) {
        float* wG = (it & 1) ? GpB : GpA;
        float* rG = (it & 1) ? GpA : GpB;
        float* wE = (it & 1) ? errpB : errpA;
        float* rE = (it & 1) ? errpA : errpB;
        k_iter<<<NBLK, BT, 0, stream>>>(p1, p2, out, rG, wG, rE, wE,
                                        rc, errs, doneflag, p1s, it);
    }
}

// Round 11
// 251.027 us; speedup vs baseline: 1.0138x; 1.0138x over previous
//
#include <hip/hip_runtime.h>

#define B 4
#define N 2048
#define MAXIT 11        // bodies it=0..10; launch it=11 is finalize-only
#define TOL 1e-4f
#define BT 256
#define NBLK 256
#define QPB 32         // queries per block
#define NSTR 32        // candidate stripes per block
#define CPS 64         // candidates per stripe
#define CPT 8          // candidates per thread (N/BT)

// ---------------- workspace layout (ping-pong partials: no memsets needed) ----
// [0,     12288) f32 GpA[64][4][12]   (G-partials: {sum m(3), sum m (x) p1(9)})
// [12288, 24576) f32 GpB[64][4][12]
// [24576, 25600) f32 errpA[256]       (per-block sum of sqrt(d2) over 32 queries)
// [25600, 26624) f32 errpB[256]
// [26624, 31232) f64 rc[B][12][12]    (cumulative R(9)+t(3) per batch per launch)
// [31232, 31280) f32 errs[12]
// [31280, 31284) int doneflag         (0 or finalize-launch-index+1)
// [31284, 31332) f32 p1s[B][3]        (sum of p1 per batch, written at it=0)

// ---------------- 3x3 helpers (double, thread-serial) ----------------
__device__ double det3(const double* M) {
    return M[0]*(M[4]*M[8]-M[5]*M[7])
         - M[1]*(M[3]*M[8]-M[5]*M[6])
         + M[2]*(M[3]*M[7]-M[4]*M[6]);
}

__device__ void svd3x3(const double* A, double* U, double* V, double* sig) {
    double S[9];
    for (int i = 0; i < 3; ++i)
        for (int j = 0; j < 3; ++j) {
            double s = 0.0;
            for (int k = 0; k < 3; ++k) s += A[k*3+i] * A[k*3+j];
            S[i*3+j] = s;
        }
    double Vm[9] = {1,0,0, 0,1,0, 0,0,1};
    for (int sweep = 0; sweep < 30; ++sweep) {
        double off = fabs(S[1]) + fabs(S[2]) + fabs(S[5]);
        double base = fabs(S[0]) + fabs(S[4]) + fabs(S[8]);
        if (off <= 1e-15 * base) break;
        for (int pi = 0; pi < 3; ++pi) {
            const int p = (pi == 2) ? 1 : 0;
            const int q = (pi == 0) ? 1 : 2;
            double apq = S[p*3+q];
            if (apq == 0.0) continue;
            double app = S[p*3+p], aqq = S[q*3+q];
            double tau = (aqq - app) / (2.0 * apq);
            double tt  = ((tau >= 0.0) ? 1.0 : -1.0) / (fabs(tau) + sqrt(1.0 + tau*tau));
            double c = 1.0 / sqrt(1.0 + tt*tt);
            double s = tt * c;
            for (int k = 0; k < 3; ++k) {
                double skp = S[k*3+p], skq = S[k*3+q];
                S[k*3+p] = c*skp - s*skq;
                S[k*3+q] = s*skp + c*skq;
            }
            for (int k = 0; k < 3; ++k) {
                double spk = S[p*3+k], sqk = S[q*3+k];
                S[p*3+k] = c*spk - s*sqk;
                S[q*3+k] = s*spk + c*sqk;
            }
            for (int k = 0; k < 3; ++k) {
                double vkp = Vm[k*3+p], vkq = Vm[k*3+q];
                Vm[k*3+p] = c*vkp - s*vkq;
                Vm[k*3+q] = s*vkp + c*vkq;
            }
        }
    }
    double lam[3] = {S[0], S[4], S[8]};
    int ord[3] = {0, 1, 2};
    for (int i = 0; i < 2; ++i)
        for (int j = i+1; j < 3; ++j)
            if (lam[ord[j]] > lam[ord[i]]) { int tmp = ord[i]; ord[i] = ord[j]; ord[j] = tmp; }
    for (int i = 0; i < 3; ++i) {
        int o = ord[i];
        double l = lam[o] > 0.0 ? lam[o] : 0.0;
        sig[i] = sqrt(l);
        for (int k = 0; k < 3; ++k) V[k*3+i] = Vm[k*3+o];
    }
    for (int i = 0; i < 3; ++i) {
        double u0 = 0, u1 = 0, u2 = 0;
        for (int k = 0; k < 3; ++k) {
            u0 += A[0*3+k] * V[k*3+i];
            u1 += A[1*3+k] * V[k*3+i];
            u2 += A[2*3+k] * V[k*3+i];
        }
        double nrm = sqrt(u0*u0 + u1*u1 + u2*u2);
        if (nrm > 1e-300) { u0 /= nrm; u1 /= nrm; u2 /= nrm; }
        else {
            double ax = U[0], ay = U[3], az = U[6];
            double bx = U[1], by = U[4], bz = U[7];
            u0 = ay*bz - az*by; u1 = az*bx - ax*bz; u2 = ax*by - ay*bx;
        }
        U[0*3+i] = u0; U[1*3+i] = u1; U[2*3+i] = u2;
    }
}

// R = V @ U^T (reference's R incl. the V[2][2]*=d quirk). Fast path det(H)>0:
// Newton polar iteration, fixed count (bit-identical across blocks).
__device__ void compute_R_f64(const double* H, double* R) {
    double nf = 0.0;
    for (int k = 0; k < 9; ++k) nf += H[k]*H[k];
    if (nf > 0.0) {
        const double sc = 1.0 / sqrt(nf * (1.0/3.0));
        double X[9];
        #pragma unroll
        for (int k = 0; k < 9; ++k) X[k] = H[k] * sc;
        const double d0 = det3(X);
        if (d0 > 1e-12) {
            for (int iter = 0; iter < 10; ++iter) {
                const double dt = det3(X);
                const double g = (iter < 4) ? cbrt(1.0 / dt) : 1.0;
                double Y[9];
                #pragma unroll
                for (int k = 0; k < 9; ++k) Y[k] = g * X[k];
                double C[9];
                C[0] = Y[4]*Y[8]-Y[5]*Y[7]; C[1] = Y[5]*Y[6]-Y[3]*Y[8]; C[2] = Y[3]*Y[7]-Y[4]*Y[6];
                C[3] = Y[2]*Y[7]-Y[1]*Y[8]; C[4] = Y[0]*Y[8]-Y[2]*Y[6]; C[5] = Y[1]*Y[6]-Y[0]*Y[7];
                C[6] = Y[1]*Y[5]-Y[2]*Y[4]; C[7] = Y[2]*Y[3]-Y[0]*Y[5]; C[8] = Y[0]*Y[4]-Y[1]*Y[3];
                const double inv = 1.0 / (dt * g * g * g);
                #pragma unroll
                for (int k = 0; k < 9; ++k) X[k] = 0.5 * (Y[k] + C[k] * inv);
            }
            R[0]=X[0]; R[1]=X[3]; R[2]=X[6];
            R[3]=X[1]; R[4]=X[4]; R[5]=X[7];
            R[6]=X[2]; R[7]=X[5]; R[8]=X[8];
            return;
        }
    }
    double U[9], V[9], sig[3];
    svd3x3(H, U, V, sig);
    double d = (det3(U) * det3(V) < 0.0) ? -1.0 : 1.0;
    V[2*3+2] *= d;
    for (int i = 0; i < 3; ++i)
        for (int j = 0; j < 3; ++j) {
            double s = 0.0;
            for (int k = 0; k < 3; ++k) s += V[i*3+k] * U[j*3+k];
            R[i*3+j] = s;
        }
}

__device__ inline float wred(float v) {
    v += __shfl_down(v, 32);
    v += __shfl_down(v, 16);
    v += __shfl_down(v, 8);
    v += __shfl_down(v, 4);
    v += __shfl_down(v, 2);
    v += __shfl_down(v, 1);
    return v;   // valid on lane 0 of each wave
}

__device__ __forceinline__ void tf3(const float* __restrict__ R, const float* __restrict__ T,
                                    float x, float y, float z,
                                    float& ox, float& oy, float& oz) {
    ox = x*R[0] + y*R[3] + z*R[6] + T[0];
    oy = x*R[1] + y*R[4] + z*R[7] + T[1];
    oz = x*R[2] + y*R[5] + z*R[8] + T[2];
}

// One launch per ICP iteration. 256 blocks: b = bid>>6, blk = bid&63.
// T14 issue-early: the R-independent global loads (p1 candidates, p2 queries)
// are issued into registers at kernel top so their latency hides under phase 1's
// partial-reduction + serial polar. The transform + LDS write happen after
// phase 1 — NN values bit-identical to the round-7 passing kernel (trajectory-
// safe; round-8's query-transform variant changed f32 rounding of err and
// diverged the done-threshold trajectory).
__global__ void __launch_bounds__(BT) k_iter(const float* __restrict__ p1,
                                             const float* __restrict__ p2,
                                             float* __restrict__ out,
                                             const float* __restrict__ rGp,
                                             float* __restrict__ wGp,
                                             const float* __restrict__ rerrp,
                                             float* __restrict__ werrp,
                                             double* __restrict__ rc,
                                             float* __restrict__ errs,
                                             int* __restrict__ doneflag,
                                             float* __restrict__ p1s,
                                             int it) {
    const int bid = blockIdx.x, tid = threadIdx.x;
    const int b = bid >> 6, blk = bid & 63;
    const int lane = tid & 63, wave = tid >> 6;

    __shared__ float4 sc4[N];              // 32 KB candidates, bank-rotated
    __shared__ float sScore[NSTR][QPB];
    __shared__ int   sIdx[NSTR][QPB];
    __shared__ float sPn[QPB], sD2[QPB];
    __shared__ int   sMi[QPB];
    __shared__ float sR[9], sT[3];
    __shared__ float lred[4][16];
    __shared__ int sFin;

    // ---------- T14 issue-early: R-independent register prefetch ----------
    float cvx[CPT], cvy[CPT], cvz[CPT];
    #pragma unroll
    for (int u = 0; u < CPT; ++u) {
        const float* cp = &p1[(b*N + tid + u*BT)*3];
        cvx[u] = cp[0]; cvy[u] = cp[1]; cvz[u] = cp[2];
    }
    const int qg = tid & 7, st = tid >> 3;   // 8 query-groups x 32 stripes
    float qx[4], qy[4], qz[4];
    #pragma unroll
    for (int k = 0; k < 4; ++k) {
        const float* pp = &p2[(b*N + blk*QPB + qg*4 + k)*3];
        qx[k] = pp[0]; qy[k] = pp[1]; qz[k] = pp[2];
    }

    if (it == 0) {
        if (tid == 0) {
            sR[0]=1.f; sR[1]=0.f; sR[2]=0.f;
            sR[3]=0.f; sR[4]=1.f; sR[5]=0.f;
            sR[6]=0.f; sR[7]=0.f; sR[8]=1.f;
            sT[0]=0.f; sT[1]=0.f; sT[2]=0.f;
            sFin = 0;
            if (bid == 0) {
                *doneflag = 0;
                for (int bb = 0; bb < B; ++bb) {
                    double* r0 = rc + (bb*12 + 0)*12;
                    r0[0]=1; r0[1]=0; r0[2]=0; r0[3]=0; r0[4]=1; r0[5]=0;
                    r0[6]=0; r0[7]=0; r0[8]=1; r0[9]=0; r0[10]=0; r0[11]=0;
                }
            }
        }
        __syncthreads();
    } else {
        // early exit only for launches strictly after the finalize launch
        { const int df = *doneflag; if (df != 0 && df <= it) return; }

        // ---------- phase 1: reduce partials, rebuild H, polar, compose ------
        float g12[12];
        if (wave == 0) {
            const float* gp = rGp + (lane*4 + b)*12;    // Gp[blk=lane][b][12]
            const float4 a0 = *(const float4*)(gp);
            const float4 a1 = *(const float4*)(gp + 4);
            const float4 a2 = *(const float4*)(gp + 8);
            g12[0]=a0.x; g12[1]=a0.y; g12[2]=a0.z; g12[3]=a0.w;
            g12[4]=a1.x; g12[5]=a1.y; g12[6]=a1.z; g12[7]=a1.w;
            g12[8]=a2.x; g12[9]=a2.y; g12[10]=a2.z; g12[11]=a2.w;
            #pragma unroll
            for (int k = 0; k < 12; ++k) g12[k] = wred(g12[k]);
        }
        float er = rerrp[tid];
        er = wred(er);
        if (lane == 0) lred[wave][0] = er;
        __syncthreads();
        if (tid == 0) {
            const float ersum = lred[0][0]+lred[1][0]+lred[2][0]+lred[3][0];
            const float errcur = ersum / (float)(B*N);
            const float errprev = (it >= 2) ? errs[it-2] : 0.0f;
            const int done = (fabsf(errprev - errcur) < TOL) ? 1 : 0;
            errs[it-1] = errcur;

            const double* rp = rc + (b*12 + (it-1))*12;
            double RP[12];
            for (int k = 0; k < 12; ++k) RP[k] = rp[k];
            const double sm0 = g12[0], sm1 = g12[1], sm2 = g12[2];
            double G[9];
            for (int k = 0; k < 9; ++k) G[k] = (double)g12[3+k];
            const double p1b0 = (double)p1s[b*3+0]/N;
            const double p1b1 = (double)p1s[b*3+1]/N;
            const double p1b2 = (double)p1s[b*3+2]/N;
            const double c2d[3] = { sm0/N, sm1/N, sm2/N };
            const double smv[3] = { sm0, sm1, sm2 };
            double c1d[3], H[9];
            for (int k = 0; k < 3; ++k)
                c1d[k] = p1b0*RP[0*3+k] + p1b1*RP[1*3+k] + p1b2*RP[2*3+k] + RP[9+k];
            for (int j = 0; j < 3; ++j)
                for (int k = 0; k < 3; ++k) {
                    const double M = G[j*3+0]*RP[0*3+k] + G[j*3+1]*RP[1*3+k]
                                   + G[j*3+2]*RP[2*3+k] + smv[j]*RP[9+k];
                    H[j*3+k] = M - (double)N * c2d[j] * c1d[k];
                }
            double Rinc[9], tinc[3];
            compute_R_f64(H, Rinc);
            for (int j = 0; j < 3; ++j)
                tinc[j] = c2d[j] - (c1d[0]*Rinc[0*3+j] + c1d[1]*Rinc[1*3+j] + c1d[2]*Rinc[2*3+j]);
            double Rn[9], tn[3];
            for (int i = 0; i < 3; ++i)
                for (int j = 0; j < 3; ++j)
                    Rn[i*3+j] = RP[i*3+0]*Rinc[0*3+j] + RP[i*3+1]*Rinc[1*3+j] + RP[i*3+2]*Rinc[2*3+j];
            for (int j = 0; j < 3; ++j)
                tn[j] = RP[9+0]*Rinc[0*3+j] + RP[9+1]*Rinc[1*3+j] + RP[9+2]*Rinc[2*3+j] + tinc[j];
            double* rn = rc + (b*12 + it)*12;
            for (int k = 0; k < 9; ++k) { rn[k] = Rn[k]; sR[k] = (float)Rn[k]; }
            for (int k = 0; k < 3; ++k) { rn[9+k] = tn[k]; sT[k] = (float)tn[k]; }
            sFin = (done || it == MAXIT) ? 1 : 0;
        }
        __syncthreads();
    }

    if (sFin == 1) {
        // ---------- finalize: _get_transform(p1, temp_final) ----------
        if (blk != 0) return;
        float pv[16];
        #pragma unroll
        for (int k = 0; k < 16; ++k) pv[k] = 0.f;
        for (int i = tid; i < N; i += BT) {
            const float* pp = &p1[(b*N + i)*3];
            const float px = pp[0], py = pp[1], pz = pp[2];
            float tx, ty, tz;
            tf3(sR, sT, px, py, pz, tx, ty, tz);        // temp_final
            pv[0] += tx; pv[1] += ty; pv[2] += tz;
            pv[3] += px; pv[4] += py; pv[5] += pz;
            pv[6] += tx*px;  pv[7]  += tx*py;  pv[8]  += tx*pz;
            pv[9] += ty*px;  pv[10] += ty*py;  pv[11] += ty*pz;
            pv[12]+= tz*px;  pv[13] += tz*py;  pv[14] += tz*pz;
        }
        #pragma unroll
        for (int k = 0; k < 15; ++k) pv[k] = wred(pv[k]);
        if (lane == 0) {
            #pragma unroll
            for (int k = 0; k < 15; ++k) lred[wave][k] = pv[k];
        }
        __syncthreads();
        if (tid == 0) {
            float a[15];
            #pragma unroll
            for (int k = 0; k < 15; ++k)
                a[k] = lred[0][k] + lred[1][k] + lred[2][k] + lred[3][k];
            double c2d[3] = { (double)a[0]/N, (double)a[1]/N, (double)a[2]/N };
            double c1d[3] = { (double)a[3]/N, (double)a[4]/N, (double)a[5]/N };
            double H[9];
            for (int j = 0; j < 3; ++j)
                for (int k = 0; k < 3; ++k)
                    H[j*3+k] = (double)a[6 + j*3 + k] - (double)N * c2d[j] * c1d[k];
            double Rf[9];
            compute_R_f64(H, Rf);
            for (int i = 0; i < 3; ++i) {
                out[b*12 + i*4 + 0] = (float)Rf[i*3+0];
                out[b*12 + i*4 + 1] = (float)Rf[i*3+1];
                out[b*12 + i*4 + 2] = (float)Rf[i*3+2];
                const double tj = c2d[i] - (c1d[0]*Rf[0*3+i] + c1d[1]*Rf[1*3+i] + c1d[2]*Rf[2*3+i]);
                out[b*12 + i*4 + 3] = (float)tj;
            }
            *doneflag = it + 1;
        }
        return;
    }

    // ---------- phase 2: NN + fused partial reductions ----------
    // write-late: transform prefetched candidates with the just-computed R,t
    #pragma unroll
    for (int u = 0; u < CPT; ++u) {
        const int c = tid + u*BT;
        float cx, cy, cz;
        tf3(sR, sT, cvx[u], cvy[u], cvz[u], cx, cy, cz);
        const int s = c >> 6, jj = c & 63;
        sc4[s*64 + ((jj + s) & 63)] =
            make_float4(cx, cy, cz, 0.5f*(cx*cx + cy*cy + cz*cz));
    }
    __syncthreads();

    if (it == 0 && blk == 0) {
        // p1 sums (identity transform at it=0 -> sc4 holds p1)
        float sx = 0.f, sy = 0.f, sz = 0.f;
        for (int i = tid; i < N; i += BT) {
            const float4 v = sc4[i];
            sx += v.x; sy += v.y; sz += v.z;
        }
        sx = wred(sx); sy = wred(sy); sz = wred(sz);
        if (lane == 0) { lred[wave][0]=sx; lred[wave][1]=sy; lred[wave][2]=sz; }
    }

    if (st == 0) {
        #pragma unroll
        for (int k = 0; k < 4; ++k)
            sPn[qg*4 + k] = qx[k]*qx[k] + qy[k]*qy[k] + qz[k]*qz[k];
    }
    float bs[4]; int bj[4];
    #pragma unroll
    for (int k = 0; k < 4; ++k) { bs[k] = __uint_as_float(0x7f7fffffu); bj[k] = 0; }
    const int base = st * CPS;
    for (int j = 0; j < CPS; ++j) {
        const float4 cd = sc4[base + ((j + st) & (CPS-1))];
        const int cidx = base + j;
        #pragma unroll
        for (int k = 0; k < 4; ++k) {
            float s = __builtin_fmaf(-qx[k], cd.x,
                      __builtin_fmaf(-qy[k], cd.y,
                      __builtin_fmaf(-qz[k], cd.z, cd.w)));
            if (s < bs[k]) { bs[k] = s; bj[k] = cidx; }
        }
    }
    #pragma unroll
    for (int k = 0; k < 4; ++k) {
        sScore[st][qg*4 + k] = bs[k];
        sIdx[st][qg*4 + k]   = bj[k];
    }
    __syncthreads();

    if (it == 0 && blk == 0 && tid == 0) {
        p1s[b*3+0] = lred[0][0]+lred[1][0]+lred[2][0]+lred[3][0];
        p1s[b*3+1] = lred[0][1]+lred[1][1]+lred[2][1]+lred[3][1];
        p1s[b*3+2] = lred[0][2]+lred[1][2]+lred[2][2]+lred[3][2];
    }

    if (tid < QPB) {
        // first-min across stripes (ascending idx = first occurrence, jnp.argmin)
        float fb = sScore[0][tid]; int fj = sIdx[0][tid];
        #pragma unroll 8
        for (int s = 1; s < NSTR; ++s) {
            const float v = sScore[s][tid]; const int vi = sIdx[s][tid];
            if (v < fb || (v == fb && vi < fj)) { fb = v; fj = vi; }
        }
        const float d2 = fmaxf(__builtin_fmaf(2.0f, fb, sPn[tid]), 0.0f);
        sMi[tid] = fj;
        sD2[tid] = d2;
    }
    __syncthreads();

    // err partial: sum sqrt(d2) over this block's 32 queries
    if (tid < 64) {
        float e = (tid < QPB) ? sqrtf(sD2[tid]) : 0.f;
        e = wred(e);
        if (tid == 0) werrp[bid] = e;
    }

    // G partials: only batch-3 blocks (reference quirk: matched = p2[:, idx[-1]])
    if (b == 3 && tid < 128) {
        const int bb = tid >> 5, nl = tid & 31;
        const int mi = sMi[nl];
        const float* mp = &p2[(bb*N + mi)*3];
        const float mx = mp[0], my = mp[1], mz = mp[2];
        const float* pp = &p1[(bb*N + blk*QPB + nl)*3];
        const float qqx = pp[0], qqy = pp[1], qqz = pp[2];
        float g[12] = { mx, my, mz,
                        mx*qqx, mx*qqy, mx*qqz,
                        my*qqx, my*qqy, my*qqz,
                        mz*qqx, mz*qqy, mz*qqz };
        #pragma unroll
        for (int k = 0; k < 12; ++k) {
            #pragma unroll
            for (int o = 16; o; o >>= 1)
                g[k] += __shfl_xor(g[k], o, 32);
        }
        if (nl == 0) {
            float* gp = wGp + (blk*4 + bb)*12;
            #pragma unroll
            for (int k = 0; k < 12; ++k) gp[k] = g[k];
        }
    }
}

extern "C" void kernel_launch(void* const* d_in, const int* in_sizes, int n_in,
                              void* d_out, int out_size, void* d_ws, size_t ws_size,
                              hipStream_t stream) {
    const float* p1 = (const float*)d_in[0];
    const float* p2 = (const float*)d_in[1];
    float* out = (float*)d_out;
    float* GpA   = (float*)d_ws;
    float* GpB   = (float*)((char*)d_ws + 12288);
    float* errpA = (float*)((char*)d_ws + 24576);
    float* errpB = (float*)((char*)d_ws + 25600);
    double* rc   = (double*)((char*)d_ws + 26624);
    float* errs  = (float*)((char*)d_ws + 31232);
    int* doneflag = (int*)((char*)d_ws + 31280);
    float* p1s   = (float*)((char*)d_ws + 31284);

    for (int it = 0; it <= MAXIT; ++it) {
        float* wG = (it & 1) ? GpB : GpA;
        float* rG = (it & 1) ? GpA : GpB;
        float* wE = (it & 1) ? errpB : errpA;
        float* rE = (it & 1) ? errpA : errpB;
        k_iter<<<NBLK, BT, 0, stream>>>(p1, p2, out, rG, wG, rE, wE,
                                        rc, errs, doneflag, p1s, it);
    }
}